// Round 3
// baseline (207.262 us; speedup 1.0000x reference)
//
#include <hip/hip_runtime.h>
#include <hip/hip_bf16.h>

#define B_    32
#define LD_   512
#define LQ_   32
#define E_    300
#define NF_   4
#define D_    304
#define M_    16
#define ALPHA_ 0.9f
#define CIN_  1212          // 3*D + E
#define KP1_  1216          // CIN padded to multiple of 64
#define NCOL_ 1056          // 33 columns * 32 batches
#define NPAD_ 1088          // 17 * 64
#define PPL_  9
#define NEG_N_ 128
#define SPLITK_ 4

typedef short short8 __attribute__((ext_vector_type(8)));
typedef float f32x4 __attribute__((ext_vector_type(4)));

__device__ __forceinline__ unsigned short f2bf(float f) {
    unsigned int x = __float_as_uint(f);
    unsigned int r = (x + 0x7FFFu + ((x >> 16) & 1u)) >> 16;
    return (unsigned short)r;
}
__device__ __forceinline__ float bf2f(unsigned short u) {
    return __uint_as_float(((unsigned int)u) << 16);
}

// ---------------------------------------------------------------------------
// Per-batch query FOFE: qfb[b][0..299] = sum_q alpha^(31-q) emb[query[b,q]].
// ---------------------------------------------------------------------------
__global__ __launch_bounds__(128) void query_fofe(
    const int* __restrict__ query, const float* __restrict__ emb,
    unsigned short* __restrict__ qfb)
{
    int b = blockIdx.x;
    __shared__ int   rows[32];
    __shared__ float wq[32];
    int tid = threadIdx.x;
    if (tid < 32) {
        rows[tid] = query[b * LQ_ + tid];
        wq[tid] = powf(ALPHA_, (float)(LQ_ - 1 - tid));
    }
    __syncthreads();
    if (tid < 76) {
        int cc = tid * 4;
        float ax = 0.f, ay = 0.f, az = 0.f, aw = 0.f;
        if (cc < 300) {
            for (int i = 0; i < 32; ++i) {
                float4 v = *(const float4*)(emb + (size_t)rows[i] * E_ + cc);
                float wv = wq[i];
                ax += wv * v.x; ay += wv * v.y; az += wv * v.z; aw += wv * v.w;
            }
        }
        ushort4 o; o.x = f2bf(ax); o.y = f2bf(ay); o.z = f2bf(az); o.w = f2bf(aw);
        *(ushort4*)(qfb + (size_t)b * 304 + cc) = o;
    }
}

// ---------------------------------------------------------------------------
// Feature builder: one block per (batch, column). Output Ft [NCOL][KP1] bf16.
// ---------------------------------------------------------------------------
__global__ __launch_bounds__(320) void build_features(
    const int* __restrict__ doc, const float* __restrict__ doc_f,
    const int* __restrict__ target_s, const int* __restrict__ target_e,
    const float* __restrict__ emb,
    const int* __restrict__ rand_length, const int* __restrict__ rand_position,
    const unsigned short* __restrict__ qfb,
    unsigned short* __restrict__ Ft)
{
    int bcol = blockIdx.x;
    int b = bcol / 33;
    int col = bcol % 33;
    __shared__ int   s_t[3][16];
    __shared__ float s_w[3][16];
    __shared__ int   s_row[3][16];
    int tid = threadIdx.x;

    if (tid < 48) {
        int part = tid >> 4, k = tid & 15;
        int t; float valid;
        if (col == 0) {
            int ts = target_s[b], te = target_e[b];
            int span = te - ts;
            if (part == 0)      { t = ts - 1 - k;  valid = (t >= 0) ? 1.f : 0.f; }
            else if (part == 1) { t = te - k;      valid = (k <= span && t >= 0) ? 1.f : 0.f; }
            else                { t = te + 1 + k;  valid = (t < LD_) ? 1.f : 0.f; }
        } else {
            int j = col - 1;
            int r = j / PPL_, p = j - r * PPL_;
            int rl = rand_length[r];
            int rp = rand_position[r * PPL_ + p];
            if (part == 0)      { t = rp - 1 - k;      valid = (t >= 0) ? 1.f : 0.f; }
            else if (part == 1) { t = rp - k;          valid = (k <= rl && t >= 0) ? 1.f : 0.f; }
            else                { t = rp + rl + 1 + k; valid = (t < LD_) ? 1.f : 0.f; }
        }
        float w = (valid != 0.f) ? powf(ALPHA_, (float)k) : 0.f;
        t = min(max(t, 0), LD_ - 1);
        s_t[part][k] = t;
        s_w[part][k] = w;
        s_row[part][k] = doc[b * LD_ + t];
    }
    __syncthreads();

    unsigned short* out = Ft + (size_t)bcol * KP1_;
    int g = tid;                       // 304 groups of 4 elements
    if (g < 228) {                     // doc parts: 3 * 76 groups
        int part = g / 76;
        int g2 = g - part * 76;
        int cc = g2 * 4;
        float ax = 0.f, ay = 0.f, az = 0.f, aw = 0.f;
        if (cc < 300) {
            for (int i = 0; i < 16; ++i) {
                float4 v = *(const float4*)(emb + (size_t)s_row[part][i] * E_ + cc);
                float wv = s_w[part][i];
                ax += wv * v.x; ay += wv * v.y; az += wv * v.z; aw += wv * v.w;
            }
        } else {
            for (int i = 0; i < 16; ++i) {
                float4 v = *(const float4*)(doc_f + ((size_t)b * LD_ + s_t[part][i]) * NF_);
                float wv = s_w[part][i];
                ax += wv * v.x; ay += wv * v.y; az += wv * v.z; aw += wv * v.w;
            }
        }
        ushort4 o; o.x = f2bf(ax); o.y = f2bf(ay); o.z = f2bf(az); o.w = f2bf(aw);
        *(ushort4*)(out + 4 * g) = o;
    } else if (g < 303) {
        *(ushort4*)(out + 4 * g) =
            *(const ushort4*)(qfb + (size_t)b * 304 + (g - 228) * 4);
    } else if (g == 303) {
        ushort4 z; z.x = 0; z.y = 0; z.z = 0; z.w = 0;
        *(ushort4*)(out + 4 * g) = z;
    }
}

// ---------------------------------------------------------------------------
// fp32 -> bf16 weight conversion, float4-vectorized. W1 K-padded to KP1.
// ---------------------------------------------------------------------------
__global__ __launch_bounds__(256) void convert_all(
    const float* __restrict__ W1, const float* __restrict__ W2,
    const float* __restrict__ W3, const float* __restrict__ W4,
    unsigned short* __restrict__ W1b, unsigned short* __restrict__ W2b,
    unsigned short* __restrict__ W3b, unsigned short* __restrict__ W4b)
{
    const long n1 = 1024L * KP1_ / 4;
    const long n2 = 1024L * 1024L / 4;
    const long n4 = 512L * 1024L / 4;
    const long total = n1 + 2 * n2 + n4;
    long stride = (long)gridDim.x * 256L;
    for (long i = (long)blockIdx.x * 256L + threadIdx.x; i < total; i += stride) {
        ushort4 o;
        if (i < n1) {
            long m = i / 304; int k4 = (int)(i - m * 304);
            if (k4 < 303) {
                float4 v = *(const float4*)(W1 + m * CIN_ + k4 * 4);
                o.x = f2bf(v.x); o.y = f2bf(v.y); o.z = f2bf(v.z); o.w = f2bf(v.w);
            } else { o.x = 0; o.y = 0; o.z = 0; o.w = 0; }
            *(ushort4*)(W1b + i * 4) = o;
        } else if (i < n1 + n2) {
            long j = i - n1;
            float4 v = *(const float4*)(W2 + j * 4);
            o.x = f2bf(v.x); o.y = f2bf(v.y); o.z = f2bf(v.z); o.w = f2bf(v.w);
            *(ushort4*)(W2b + j * 4) = o;
        } else if (i < n1 + 2 * n2) {
            long j = i - n1 - n2;
            float4 v = *(const float4*)(W3 + j * 4);
            o.x = f2bf(v.x); o.y = f2bf(v.y); o.z = f2bf(v.z); o.w = f2bf(v.w);
            *(ushort4*)(W3b + j * 4) = o;
        } else {
            long j = i - n1 - 2 * n2;
            float4 v = *(const float4*)(W4 + j * 4);
            o.x = f2bf(v.x); o.y = f2bf(v.y); o.z = f2bf(v.z); o.w = f2bf(v.w);
            *(ushort4*)(W4b + j * 4) = o;
        }
    }
}

// ---------------------------------------------------------------------------
// Split-K bf16 MFMA GEMM. blockIdx.z = K-chunk; each chunk writes fp32
// partials to its own slice of P (stride sliceStride). 64x64 tile,
// double-buffered LDS, BK=64. A:[MxK] bf16, Bm:[NxK] bf16, P: fp32 [N][M].
// ---------------------------------------------------------------------------
__global__ __launch_bounds__(256) void gemm_splitk(
    const unsigned short* __restrict__ A,
    const unsigned short* __restrict__ Bm,
    float* __restrict__ P,
    int M, int K, int KCI)          // KCI = BK64 iterations per chunk
{
    __shared__ unsigned short As[2][64][72];
    __shared__ unsigned short Bs[2][64][72];
    int tid = threadIdx.x;
    int m0 = blockIdx.x * 64, n0 = blockIdx.y * 64;
    int z = blockIdx.z;
    int nk = (K + 63) >> 6;
    int kb = z * KCI;
    int ke = min(nk, kb + KCI);
    int w = tid >> 6, lane = tid & 63;
    int wm = (w >> 1) * 32, wn = (w & 1) * 32;
    int lr = tid >> 2;
    int ls = (tid & 3) * 16;
    int fr = lane & 15, fk = (lane >> 4) * 8;

    const unsigned short* Arow = A + (size_t)(m0 + lr) * K + ls;
    const unsigned short* Brow = Bm + (size_t)(n0 + lr) * K + ls;

    f32x4 acc00 = {0.f,0.f,0.f,0.f}, acc01 = {0.f,0.f,0.f,0.f};
    f32x4 acc10 = {0.f,0.f,0.f,0.f}, acc11 = {0.f,0.f,0.f,0.f};

    {   // prologue: tile kb -> buf 0
        const unsigned short* An = Arow + (size_t)kb * 64;
        const unsigned short* Bn = Brow + (size_t)kb * 64;
        *(uint4*)&As[0][lr][ls]     = *(const uint4*)(An);
        *(uint4*)&As[0][lr][ls + 8] = *(const uint4*)(An + 8);
        *(uint4*)&Bs[0][lr][ls]     = *(const uint4*)(Bn);
        *(uint4*)&Bs[0][lr][ls + 8] = *(const uint4*)(Bn + 8);
    }
    __syncthreads();
    int cur = 0;
    for (int i = kb; i < ke; ++i) {
        uint4 na0, na1, nb0, nb1;
        bool more = (i + 1 < ke);
        if (more) {
            const unsigned short* An = Arow + (size_t)(i + 1) * 64;
            const unsigned short* Bn = Brow + (size_t)(i + 1) * 64;
            na0 = *(const uint4*)(An);
            na1 = *(const uint4*)(An + 8);
            nb0 = *(const uint4*)(Bn);
            nb1 = *(const uint4*)(Bn + 8);
        }
        #pragma unroll
        for (int s = 0; s < 2; ++s) {
            short8 fa0 = *(const short8*)&As[cur][wm + fr][s * 32 + fk];
            short8 fa1 = *(const short8*)&As[cur][wm + 16 + fr][s * 32 + fk];
            short8 fb0 = *(const short8*)&Bs[cur][wn + fr][s * 32 + fk];
            short8 fb1 = *(const short8*)&Bs[cur][wn + 16 + fr][s * 32 + fk];
            acc00 = __builtin_amdgcn_mfma_f32_16x16x32_bf16(fa0, fb0, acc00, 0, 0, 0);
            acc01 = __builtin_amdgcn_mfma_f32_16x16x32_bf16(fa0, fb1, acc01, 0, 0, 0);
            acc10 = __builtin_amdgcn_mfma_f32_16x16x32_bf16(fa1, fb0, acc10, 0, 0, 0);
            acc11 = __builtin_amdgcn_mfma_f32_16x16x32_bf16(fa1, fb1, acc11, 0, 0, 0);
        }
        if (more) {
            int nb = cur ^ 1;
            *(uint4*)&As[nb][lr][ls]     = na0;
            *(uint4*)&As[nb][lr][ls + 8] = na1;
            *(uint4*)&Bs[nb][lr][ls]     = nb0;
            *(uint4*)&Bs[nb][lr][ls + 8] = nb1;
        }
        __syncthreads();
        cur ^= 1;
    }

    float* Pz = P + (size_t)z * NPAD_ * M;
    int rbase = (lane >> 4) * 4;
    int cb = lane & 15;
    #define STORE_TILE(ACC, MT, NT) do {                                   \
        int m = m0 + wm + (MT) * 16 + rbase;                               \
        int n = n0 + wn + (NT) * 16 + cb;                                  \
        *(f32x4*)(Pz + (size_t)n * M + m) = (ACC);                         \
    } while (0)
    STORE_TILE(acc00, 0, 0);
    STORE_TILE(acc01, 0, 1);
    STORE_TILE(acc10, 1, 0);
    STORE_TILE(acc11, 1, 1);
    #undef STORE_TILE
}

// ---------------------------------------------------------------------------
// Reduce 4 split-K fp32 partial slices + ReLU + bf16 convert.
// ---------------------------------------------------------------------------
__global__ __launch_bounds__(256) void reduce_relu(
    const float* __restrict__ P, unsigned short* __restrict__ out, int M)
{
    size_t SS = (size_t)NPAD_ * M;
    size_t idx = ((size_t)blockIdx.x * 256 + threadIdx.x) * 4;
    float4 a = *(const float4*)(P + idx);
    float4 b = *(const float4*)(P + SS + idx);
    float4 c = *(const float4*)(P + 2 * SS + idx);
    float4 d = *(const float4*)(P + 3 * SS + idx);
    ushort4 o;
    o.x = f2bf(fmaxf(a.x + b.x + c.x + d.x, 0.f));
    o.y = f2bf(fmaxf(a.y + b.y + c.y + d.y, 0.f));
    o.z = f2bf(fmaxf(a.z + b.z + c.z + d.z, 0.f));
    o.w = f2bf(fmaxf(a.w + b.w + c.w + d.w, 0.f));
    *(ushort4*)(out + idx) = o;
}

// ---------------------------------------------------------------------------
// Fused layer-4 reduce + ReLU + score + loss. One wave per column; sums the
// 4 fp32 partial slices of h4 (M=512), relu, sigmoid(W5.h), weighted square.
// ---------------------------------------------------------------------------
__global__ __launch_bounds__(256) void score_loss(
    const float* __restrict__ P,     // 4 slices [NPAD][512] fp32
    const float* __restrict__ W5, const int* __restrict__ rand_idx,
    float* __restrict__ out)
{
    __shared__ int cnt[32];
    __shared__ float part[4];
    int tid = threadIdx.x;
    if (tid < 32) cnt[tid] = 0;
    __syncthreads();
    if (tid < NEG_N_) atomicAdd(&cnt[rand_idx[tid]], 1);
    __syncthreads();
    int w = tid >> 6, lane = tid & 63;
    int col = blockIdx.x * 4 + w;
    const size_t SS = (size_t)NPAD_ * 512;
    const float* row = P + (size_t)col * 512 + lane * 8;
    float4 s0 = {0.f,0.f,0.f,0.f}, s1 = {0.f,0.f,0.f,0.f};
    #pragma unroll
    for (int zz = 0; zz < SPLITK_; ++zz) {
        float4 a = *(const float4*)(row + zz * SS);
        float4 b = *(const float4*)(row + zz * SS + 4);
        s0.x += a.x; s0.y += a.y; s0.z += a.z; s0.w += a.w;
        s1.x += b.x; s1.y += b.y; s1.z += b.z; s1.w += b.w;
    }
    const float* w5 = W5 + lane * 8;
    float z = fmaxf(s0.x, 0.f) * w5[0] + fmaxf(s0.y, 0.f) * w5[1] +
              fmaxf(s0.z, 0.f) * w5[2] + fmaxf(s0.w, 0.f) * w5[3] +
              fmaxf(s1.x, 0.f) * w5[4] + fmaxf(s1.y, 0.f) * w5[5] +
              fmaxf(s1.z, 0.f) * w5[6] + fmaxf(s1.w, 0.f) * w5[7];
    for (int off = 32; off > 0; off >>= 1) z += __shfl_down(z, off, 64);
    if (lane == 0) {
        float s = 1.f / (1.f + expf(-z));
        int c33 = col % 33;
        float v;
        if (c33 == 0) { float d = s - 1.f; v = 128.f * d * d; }
        else          { v = (float)cnt[c33 - 1] * s * s; }
        part[w] = v;
    }
    __syncthreads();
    if (tid == 0) atomicAdd(out, part[0] + part[1] + part[2] + part[3]);
}

extern "C" void kernel_launch(void* const* d_in, const int* in_sizes, int n_in,
                              void* d_out, int out_size, void* d_ws, size_t ws_size,
                              hipStream_t stream)
{
    const int*   doc        = (const int*)d_in[0];
    const float* doc_f      = (const float*)d_in[1];
    const int*   query      = (const int*)d_in[2];
    const int*   target_s   = (const int*)d_in[3];
    const int*   target_e   = (const int*)d_in[4];
    const float* emb        = (const float*)d_in[7];
    const float* W1         = (const float*)d_in[8];
    const float* W2         = (const float*)d_in[9];
    const float* W3         = (const float*)d_in[10];
    const float* W4         = (const float*)d_in[11];
    const float* W5         = (const float*)d_in[12];
    const int*   rand_length   = (const int*)d_in[13];
    const int*   rand_position = (const int*)d_in[14];
    const int*   rand_idx      = (const int*)d_in[15];

    char* ws = (char*)d_ws;
    size_t off = 0;
    auto alloc = [&](size_t bytes) {
        void* p = ws + off;
        off = (off + bytes + 255) & ~(size_t)255;
        return p;
    };
    unsigned short* W1b = (unsigned short*)alloc((size_t)1024 * KP1_ * 2);
    unsigned short* W2b = (unsigned short*)alloc((size_t)1024 * 1024 * 2);
    unsigned short* W3b = (unsigned short*)alloc((size_t)1024 * 1024 * 2);
    unsigned short* W4b = (unsigned short*)alloc((size_t)512 * 1024 * 2);
    unsigned short* Ft  = (unsigned short*)alloc((size_t)NPAD_ * KP1_ * 2);
    unsigned short* hA  = (unsigned short*)alloc((size_t)NPAD_ * 1024 * 2);
    unsigned short* hB  = (unsigned short*)alloc((size_t)NPAD_ * 1024 * 2);
    unsigned short* qfb = (unsigned short*)alloc((size_t)B_ * 304 * 2);
    float* P            = (float*)alloc((size_t)SPLITK_ * NPAD_ * 1024 * 4);
    float* d_loss = (float*)d_out;
    (void)ws_size; (void)in_sizes; (void)n_in; (void)out_size;

    hipMemsetAsync(Ft + (size_t)NCOL_ * KP1_, 0,
                   (size_t)(NPAD_ - NCOL_) * KP1_ * 2, stream);
    hipMemsetAsync(d_loss, 0, sizeof(float), stream);

    convert_all<<<dim3(3776), dim3(256), 0, stream>>>(W1, W2, W3, W4,
                                                      W1b, W2b, W3b, W4b);
    query_fofe<<<dim3(B_), dim3(128), 0, stream>>>(query, emb, qfb);
    build_features<<<dim3(NCOL_), dim3(320), 0, stream>>>(
        doc, doc_f, target_s, target_e, emb,
        rand_length, rand_position, qfb, Ft);

    // L1: K=1216 -> 19 BK64 iters, chunks of 5/5/5/4
    gemm_splitk<<<dim3(16, 17, SPLITK_), dim3(256), 0, stream>>>(W1b, Ft, P, 1024, KP1_, 5);
    reduce_relu<<<dim3(1088), dim3(256), 0, stream>>>(P, hA, 1024);
    gemm_splitk<<<dim3(16, 17, SPLITK_), dim3(256), 0, stream>>>(W2b, hA, P, 1024, 1024, 4);
    reduce_relu<<<dim3(1088), dim3(256), 0, stream>>>(P, hB, 1024);
    gemm_splitk<<<dim3(16, 17, SPLITK_), dim3(256), 0, stream>>>(W3b, hB, P, 1024, 1024, 4);
    reduce_relu<<<dim3(1088), dim3(256), 0, stream>>>(P, hA, 1024);
    gemm_splitk<<<dim3(8, 17, SPLITK_), dim3(256), 0, stream>>>(W4b, hA, P, 512, 1024, 4);

    score_loss<<<dim3(NCOL_ / 4), dim3(256), 0, stream>>>(P, W5, rand_idx, d_loss);
}